// Round 5
// baseline (143.109 us; speedup 1.0000x reference)
//
#include <hip/hip_runtime.h>
#include <hip/hip_bf16.h>
#include <math.h>

// Problem shape (fixed): x [B,T,D] fp32, log_alpha scalar fp32, out [B,T,D] fp32.
#define B_ 4
#define T_ 4096
#define D_ 512
#define BT 128                 // t/s tile size per block (128x128 pair)
#define BK 64                  // K elems per pipeline step (fp8: 64 B/row)
#define STEPS (D_ / BK)        // 8
#define NT (T_ / BT)           // 32 tiles per batch
#define NPAIR (NT * (NT + 1) / 2)  // 528 lower-triangle tile pairs

// Workspace layout:
//   [0 .. 64KiB)                maxsim as order-preserving uint32 [B*T]
//   [64KiB .. 64KiB+B*T*D)      xn: normalized rows, fp8 e4m3, UNIT-INTERLEAVED:
//     within each 64-elem K-slab, 16B chunk C holds logical 8B units
//     {elems C*8..C*8+7} (h=0) then {elems 32+C*8..+7} (h=1). One ds_read_b128
//     serves both MFMA k-halves of a row (R2-verified zero-conflict pattern).

typedef float f32x4 __attribute__((ext_vector_type(4)));
typedef long i64x2 __attribute__((ext_vector_type(2)));

// monotone float -> uint so unsigned atomicMax orders like float
__device__ __forceinline__ unsigned f2ord(float f) {
    unsigned u = __float_as_uint(f);
    return (u & 0x80000000u) ? ~u : (u | 0x80000000u);
}
__device__ __forceinline__ float ord2f(unsigned u) {
    unsigned b = (u & 0x80000000u) ? (u ^ 0x80000000u) : ~u;
    return __uint_as_float(b);
}

__device__ __forceinline__ void async16(const unsigned char* g, unsigned char* l) {
    // 16B/lane global->LDS DMA; LDS dest = wave-uniform base + lane*16
    __builtin_amdgcn_global_load_lds(
        (const __attribute__((address_space(1))) unsigned int*)g,
        (__attribute__((address_space(3))) unsigned int*)l, 16, 0, 0);
}

// ---- Kernel 1: one wave per row. inv-norm + permuted fp8 write + init ----
__global__ __launch_bounds__(256) void k_norm(const float* __restrict__ x,
                                              unsigned char* __restrict__ xn,
                                              unsigned* __restrict__ maxsim) {
    int w = (blockIdx.x * 256 + threadIdx.x) >> 6;   // row id (B*T rows)
    int l = threadIdx.x & 63;
    const float4* xr = (const float4*)(x + (size_t)w * D_);
    float4 a = xr[l];             // elems 4l..4l+3
    float4 b = xr[l + 64];        // elems 256+4l..
    float ss = a.x * a.x + a.y * a.y + a.z * a.z + a.w * a.w +
               b.x * b.x + b.y * b.y + b.z * b.z + b.w * b.w;
#pragma unroll
    for (int off = 32; off > 0; off >>= 1) ss += __shfl_xor(ss, off);
    float inv = 1.0f / fmaxf(sqrtf(ss), 1e-12f);
    int u0 = __builtin_amdgcn_cvt_pk_fp8_f32(a.x * inv, a.y * inv, 0, false);
    u0 = __builtin_amdgcn_cvt_pk_fp8_f32(a.z * inv, a.w * inv, u0, true);
    int u1 = __builtin_amdgcn_cvt_pk_fp8_f32(b.x * inv, b.y * inv, 0, false);
    u1 = __builtin_amdgcn_cvt_pk_fp8_f32(b.z * inv, b.w * inv, u1, true);
    // permuted address (in uints) for elem group e0=4l:
    //   slab (l>>4)*16 | chunk ((l>>1)&3)*4 | half ((l>>3)&1)*2 | (l&1)
    unsigned* xo = (unsigned*)(xn + (size_t)w * D_);
    int off4 = (l >> 4) * 16 + ((l >> 1) & 3) * 4 + ((l >> 3) & 1) * 2 + (l & 1);
    xo[off4]      = (unsigned)u0;   // elems 4l..4l+3
    xo[off4 + 64] = (unsigned)u1;   // elems 256+4l.. (+4 slabs = +256 B)
    if (l == 0) maxsim[w] = f2ord(-2.0f);
}

// ---- Kernel 2: one block per (ti,si) pair; fp8 MFMA; BARRIER-FREE pipeline ----
// R14 delta: wave-private staging kills the per-step s_barrier (the counter-
// diagnosed stall: all barrier-family variants R0/R2/R3/R4 sit at MfmaUtil
// 23-29%, step time ~4400 cyc vs ~300 cyc issued work/wave). Each wave
// (wm,wn) stages its OWN A-half (64 rows) + B-half (64 rows) per K-step into
// a private 8 KB LDS region: 2x duplicated DMA (L2-resident, ~540 MB total
// at ~20 TB/s << 34.5 TB/s L2 ceiling) buys ZERO cross-wave dependencies.
// Loop: counted vmcnt(8) (own loads) -> ds_read frags -> lgkmcnt(0) (needed
// before MFMA anyway; frees the buffer) -> STAGE(k+2) into freed buffer ->
// 32 MFMA. No s_barrier in the kernel (AITER's never-drain pattern). LDS
// 4 waves x 2 stages x 8 KB = 64 KB -> 2 blocks/CU (8 waves, free-running).
// Per-wave compute bit-identical to R0: acc[4][4], chunk-XOR swizzle
// (row-phase (r>>1)&3 invariant to the new 16/8 KB-aligned bases), 8
// ds_read_b128 + 32 MFMA per step, same epilogue.
// History: (256,4) spilled (R2); bf16-BK=64 killed occupancy (R3); global-
// direct frags TA-bound (R5); 1-wave blocks no TLP (R7); 256x128 tile lost
// to occupancy+tail (R8); b64 frag reads 4-way conflicted (R9); scaled
// 32x32x64 MFMA restructure latency-exposed (R10); XCD remap +9us -- xn
// cache-resident (R11); pair-fusion epilogue not in shadow (R12); 8-wave
// barrier'd blocks: occupancy 49% but 57us -- barrier cost scales with
// waves, occupancy was NOT the limiter (R13).
__global__ __launch_bounds__(256) void k_maxsim(const unsigned char* __restrict__ xn,
                                                unsigned* __restrict__ maxsim) {
    __shared__ __align__(16) unsigned char Buf[4][2][8192];  // [wave][stage][A 4K | B 4K]
    const int b = blockIdx.y;
    const int p = blockIdx.x;
    // triangular decode p -> (ti, si), si <= ti
    int ti = (int)((sqrtf(8.0f * (float)p + 1.0f) - 1.0f) * 0.5f);
    while ((ti + 1) * (ti + 2) / 2 <= p) ti++;
    while (ti * (ti + 1) / 2 > p) ti--;
    const int si = p - ti * (ti + 1) / 2;
    const int t0 = ti * BT, s0 = si * BT;

    const int tid = threadIdx.x;
    const int wave = tid >> 6, lane = tid & 63;
    const int wm = wave >> 1, wn = wave & 1;     // 2x2 waves -> 64x64 each
    const int qa = lane >> 4, la = lane & 15;
    const int swz = (la >> 1) & 3;               // read-side row-phase XOR

    // wave-private global panels: A rows [t0+wm*64, +64), B rows [s0+wn*64, +64)
    const unsigned char* Ab = xn + (size_t)(b * T_ + t0 + wm * 64) * D_;
    const unsigned char* Bb = xn + (size_t)(b * T_ + s0 + wn * 64) * D_;

    // DMA: 8 async16/stage/wave. Instr q (0..3) covers private rows q*16+(lane>>2);
    // lane's 16B chunk position = (lane&3) ^ ((row>>1)&3)  [q*16 even in (r>>1)&3,
    // so the XOR term is lane-only]. LDS dest: contiguous chunk q*1024 + lane*16.
    const int rl = lane >> 2, gl = (lane & 3) ^ ((rl >> 1) & 3);
    const unsigned char* gAq[4];
    const unsigned char* gBq[4];
#pragma unroll
    for (int q = 0; q < 4; q++) {
        gAq[q] = Ab + (size_t)(q * 16 + rl) * D_ + gl * 16;
        gBq[q] = Bb + (size_t)(q * 16 + rl) * D_ + gl * 16;
    }
    unsigned char* const lw = &Buf[wave][0][0];  // wave-private 16 KB

#define STAGE(step, st)                                                  \
    do {                                                                 \
        _Pragma("unroll")                                                \
        for (int q = 0; q < 4; q++) {                                    \
            async16(gAq[q] + (step) * BK, lw + (st) * 8192 + q * 1024);  \
            async16(gBq[q] + (step) * BK, lw + (st) * 8192 + 4096 + q * 1024); \
        }                                                                \
    } while (0)

    f32x4 acc[4][4];
#pragma unroll
    for (int i = 0; i < 4; i++)
#pragma unroll
        for (int j = 0; j < 4; j++) acc[i][j] = (f32x4){0.f, 0.f, 0.f, 0.f};

    const int rpos = (qa ^ swz) * 16;            // b128 position within 64-B row

    // prologue: steps 0 and 1 in flight (8 DMA instrs each per wave)
    STAGE(0, 0);
    STAGE(1, 1);

#pragma unroll
    for (int k = 0; k < STEPS; ++k) {
        const int cur = k & 1;
        // simm16: vmcnt lo[3:0] | expcnt(7)<<4 | lgkmcnt(15)<<8 | vmcnt hi[15:14]
        if (k == STEPS - 1) __builtin_amdgcn_s_waitcnt(0x0F70);  // vmcnt(0)
        else                __builtin_amdgcn_s_waitcnt(0x0F78);  // vmcnt(8): stage k landed
        __asm__ __volatile__("" ::: "memory");   // pin LDS reads below the wait

        const unsigned char* As = lw + cur * 8192;
        const unsigned char* Bs = As + 4096;
        // ONE b128 per row: [0]=h0 fragment (k 0..31), [1]=h1 (k 32..63)
        i64x2 af[4], bfr[4];
#pragma unroll
        for (int i = 0; i < 4; i++)
            af[i] = *(const i64x2*)&As[(i * 16 + la) * 64 + rpos];
#pragma unroll
        for (int j = 0; j < 4; j++)
            bfr[j] = *(const i64x2*)&Bs[(j * 16 + la) * 64 + rpos];
        // frags now requested; drain LDS reads (needed before MFMA anyway) so
        // the buffer can be legally overwritten by the next DMA stage.
        __builtin_amdgcn_s_waitcnt(0xC07F);      // lgkmcnt(0), vmcnt(63)
        __asm__ __volatile__("" ::: "memory");
        if (k + 2 < STEPS) STAGE(k + 2, cur);

#pragma unroll
        for (int h = 0; h < 2; h++)
#pragma unroll
            for (int i = 0; i < 4; i++)
#pragma unroll
                for (int j = 0; j < 4; j++)
                    acc[i][j] = __builtin_amdgcn_mfma_f32_16x16x32_fp8_fp8(
                        af[i][h], bfr[j][h], acc[i][j], 0, 0, 0);
    }
#undef STAGE

    // epilogue: per-row max over this tile's s-columns, then global atomicMax.
    // C/D layout (verified, dtype-independent): col = lane&15, row = (lane>>4)*4+reg
    const bool diag = (ti == si);
#pragma unroll
    for (int i = 0; i < 4; i++) {
#pragma unroll
        for (int r = 0; r < 4; r++) {
            int tl = wm * 64 + i * 16 + qa * 4 + r;   // local t row
            float m = -2.0f;
#pragma unroll
            for (int j = 0; j < 4; j++) {
                int sl = wn * 64 + j * 16 + la;       // local s col
                float v = acc[i][j][r];
                if (!diag || sl < tl) m = fmaxf(m, v);
            }
#pragma unroll
            for (int off = 1; off < 16; off <<= 1) m = fmaxf(m, __shfl_xor(m, off));
            if (la == 0) atomicMax(&maxsim[b * T_ + t0 + tl], f2ord(m));
        }
    }
}

// ---- Kernel 3: gate + tanh-GELU, one float4 per thread ----
__device__ __forceinline__ float gelu_tanh(float y) {
    float t = tanhf(0.7978845608028654f * (y + 0.044715f * y * y * y));
    return 0.5f * y * (1.0f + t);
}

__global__ __launch_bounds__(256) void k_gate(const float* __restrict__ x,
                                              const float* __restrict__ log_alpha,
                                              const unsigned* __restrict__ maxsim,
                                              float* __restrict__ out) {
    int idx = blockIdx.x * 256 + threadIdx.x;     // one float4 per thread
    float la = log_alpha[0];
    float alpha = (la > 20.0f) ? la : log1pf(expf(la));
    int row = idx >> 7;                           // 128 float4-threads per row
    float m = fmaxf(ord2f(maxsim[row]), -1.0f);
    float novelty = 1.0f - (m + 1.0f) * 0.5f;
    float gate = 1.0f + alpha * novelty;
    float4 v = ((const float4*)x)[idx];
    float4 o;
    o.x = gelu_tanh(v.x * gate);
    o.y = gelu_tanh(v.y * gate);
    o.z = gelu_tanh(v.z * gate);
    o.w = gelu_tanh(v.w * gate);
    ((float4*)out)[idx] = o;
}

extern "C" void kernel_launch(void* const* d_in, const int* in_sizes, int n_in,
                              void* d_out, int out_size, void* d_ws, size_t ws_size,
                              hipStream_t stream) {
    const float* x = (const float*)d_in[0];
    const float* log_alpha = (const float*)d_in[1];
    float* out = (float*)d_out;

    unsigned* maxsim = (unsigned*)d_ws;
    unsigned char* xn = (unsigned char*)d_ws + 65536;

    const int rows = B_ * T_;                     // 16384
    k_norm<<<rows / 4, 256, 0, stream>>>(x, xn, maxsim);

    dim3 g2(NPAIR, B_);
    k_maxsim<<<g2, 256, 0, stream>>>(xn, maxsim);

    k_gate<<<(B_ * T_ * D_ / 4) / 256, 256, 0, stream>>>(x, log_alpha, maxsim, out);
}

// Round 6
// 127.523 us; speedup vs baseline: 1.1222x; 1.1222x over previous
//
#include <hip/hip_runtime.h>
#include <hip/hip_bf16.h>
#include <math.h>

// Problem shape (fixed): x [B,T,D] fp32, log_alpha scalar fp32, out [B,T,D] fp32.
#define B_ 4
#define T_ 4096
#define D_ 512
#define BT 128                 // t/s tile size per block (128x128 pair)
#define BK 64                  // K elems per pipeline step (fp8: 64 B/row)
#define STEPS (D_ / BK)        // 8
#define NT (T_ / BT)           // 32 tiles per batch
#define NPAIR (NT * (NT + 1) / 2)  // 528 lower-triangle tile pairs

// Workspace layout:
//   [0 .. 64KiB)                maxsim as order-preserving uint32 [B*T]
//   [64KiB .. 64KiB+B*T*D)      xn: normalized rows, fp8 e4m3, UNIT-INTERLEAVED:
//     within each 64-elem K-slab, 16B chunk C holds logical 8B units
//     {elems C*8..C*8+7} (h=0) then {elems 32+C*8..+7} (h=1). This makes one
//     ds_read_b128 serve both MFMA k-halves of a row -> R2's verified
//     zero-conflict LDS read pattern (vs R9's 4-way-conflicted b64 reads).

typedef float f32x4 __attribute__((ext_vector_type(4)));
typedef long i64x2 __attribute__((ext_vector_type(2)));

// monotone float -> uint so unsigned atomicMax orders like float
__device__ __forceinline__ unsigned f2ord(float f) {
    unsigned u = __float_as_uint(f);
    return (u & 0x80000000u) ? ~u : (u | 0x80000000u);
}
__device__ __forceinline__ float ord2f(unsigned u) {
    unsigned b = (u & 0x80000000u) ? (u ^ 0x80000000u) : ~u;
    return __uint_as_float(b);
}

__device__ __forceinline__ void async16(const unsigned char* g, unsigned char* l) {
    // 16B/lane global->LDS DMA; LDS dest = wave-uniform base + lane*16
    __builtin_amdgcn_global_load_lds(
        (const __attribute__((address_space(1))) unsigned int*)g,
        (__attribute__((address_space(3))) unsigned int*)l, 16, 0, 0);
}

// ---- Kernel 1: one wave per row. inv-norm + permuted fp8 write + init ----
__global__ __launch_bounds__(256) void k_norm(const float* __restrict__ x,
                                              unsigned char* __restrict__ xn,
                                              unsigned* __restrict__ maxsim) {
    int w = (blockIdx.x * 256 + threadIdx.x) >> 6;   // row id (B*T rows)
    int l = threadIdx.x & 63;
    const float4* xr = (const float4*)(x + (size_t)w * D_);
    float4 a = xr[l];             // elems 4l..4l+3
    float4 b = xr[l + 64];        // elems 256+4l..
    float ss = a.x * a.x + a.y * a.y + a.z * a.z + a.w * a.w +
               b.x * b.x + b.y * b.y + b.z * b.z + b.w * b.w;
#pragma unroll
    for (int off = 32; off > 0; off >>= 1) ss += __shfl_xor(ss, off);
    float inv = 1.0f / fmaxf(sqrtf(ss), 1e-12f);
    int u0 = __builtin_amdgcn_cvt_pk_fp8_f32(a.x * inv, a.y * inv, 0, false);
    u0 = __builtin_amdgcn_cvt_pk_fp8_f32(a.z * inv, a.w * inv, u0, true);
    int u1 = __builtin_amdgcn_cvt_pk_fp8_f32(b.x * inv, b.y * inv, 0, false);
    u1 = __builtin_amdgcn_cvt_pk_fp8_f32(b.z * inv, b.w * inv, u1, true);
    // permuted address (in uints) for elem group e0=4l:
    //   slab (l>>4)*16 | chunk ((l>>1)&3)*4 | half ((l>>3)&1)*2 | (l&1)
    unsigned* xo = (unsigned*)(xn + (size_t)w * D_);
    int off4 = (l >> 4) * 16 + ((l >> 1) & 3) * 4 + ((l >> 3) & 1) * 2 + (l & 1);
    xo[off4]      = (unsigned)u0;   // elems 4l..4l+3
    xo[off4 + 64] = (unsigned)u1;   // elems 256+4l.. (+4 slabs = +256 B)
    if (l == 0) maxsim[w] = f2ord(-2.0f);
}

// ---- Kernel 2: one block per (ti,si) pair; fp8 MFMA; R6 3-stage pipeline ----
// EXACT R0 restore (the verified 131.3us configuration). 3-stage circular
// DMA buffer, ONE raw s_barrier per K-step, in-loop wait vmcnt(4). BK=64
// fp8: 16 KB/stage, 8 steps, 32 MFMA/step. LDS per stage: A[128 rows][64 B]
// then B at +8192. Chunk-XOR swizzle (R2-verified ZERO conflicts): 16B
// chunk at position P of row r holds global chunk P ^ ((r>>1)&3); reader
// b128 at position qa^((la>>1)&3) gets both k-half fragments.
// Session post-mortems (k_maxsim us): R0 41.7 BEST; XCD remap 50.5 (xn is
// cache-resident, reorder only disrupted -- R11); pair fusion 43.9
// (epilogue not in shadow -- R12); 8-wave 56.7 (occupancy was confirmed
// raised to 49% yet slower -- occupancy not the limiter -- R13); barrier-
// free wave-private 66.0 (barrier itself not the stall either -- R14);
// scaled 32x32x64 MFMA 140 (latency-exposed -- R10). Five mechanisms
// confirmed-by-counters yet regressed: sharp local optimum; schedule kept.
__global__ __launch_bounds__(256) void k_maxsim(const unsigned char* __restrict__ xn,
                                                unsigned* __restrict__ maxsim) {
    __shared__ __align__(16) unsigned char Buf[3][16384];
    const int b = blockIdx.y;
    const int p = blockIdx.x;
    // triangular decode p -> (ti, si), si <= ti
    int ti = (int)((sqrtf(8.0f * (float)p + 1.0f) - 1.0f) * 0.5f);
    while ((ti + 1) * (ti + 2) / 2 <= p) ti++;
    while (ti * (ti + 1) / 2 > p) ti--;
    const int si = p - ti * (ti + 1) / 2;
    const int t0 = ti * BT, s0 = si * BT;

    const int tid = threadIdx.x;
    const int wave = tid >> 6, lane = tid & 63;
    const int wm = wave >> 1, wn = wave & 1;     // 2x2 waves -> 64x64 each
    const int qa = lane >> 4, la = lane & 15;
    const int swz = (la >> 1) & 3;               // read-side row-phase XOR

    const unsigned char* Ab = xn + (size_t)(b * T_ + t0) * D_;
    const unsigned char* Bb = xn + (size_t)(b * T_ + s0) * D_;

    // DMA addressing: chunk index c -> row r = c>>2 (4x16B chunks = 64 B/row),
    // position c&3 holds global chunk g = (c&3) ^ ((r>>1)&3).
    const int c0 = tid,       r0_ = c0 >> 2, g0 = (c0 & 3) ^ ((r0_ >> 1) & 3);
    const int c1 = 256 + tid, r1_ = c1 >> 2, g1 = (c1 & 3) ^ ((r1_ >> 1) & 3);
    const unsigned char* gA0 = Ab + (size_t)r0_ * D_ + g0 * 16;
    const unsigned char* gA1 = Ab + (size_t)r1_ * D_ + g1 * 16;
    const unsigned char* gB0 = Bb + (size_t)r0_ * D_ + g0 * 16;
    const unsigned char* gB1 = Bb + (size_t)r1_ * D_ + g1 * 16;
    const int ldsb0 = (wave * 64) * 16;          // wave-uniform chunk base (bytes)
    const int ldsb1 = (256 + wave * 64) * 16;

#define STAGE(step, st)                                            \
    do {                                                           \
        async16(gA0 + (step) * BK, &Buf[st][ldsb0]);               \
        async16(gB0 + (step) * BK, &Buf[st][8192 + ldsb0]);        \
        async16(gA1 + (step) * BK, &Buf[st][ldsb1]);               \
        async16(gB1 + (step) * BK, &Buf[st][8192 + ldsb1]);        \
    } while (0)

    f32x4 acc[4][4];
#pragma unroll
    for (int i = 0; i < 4; i++)
#pragma unroll
        for (int j = 0; j < 4; j++) acc[i][j] = (f32x4){0.f, 0.f, 0.f, 0.f};

    const int rpos = (qa ^ swz) * 16;            // b128 position within 64-B row

    // prologue: steps 0 and 1 in flight (4 DMA instrs each per wave)
    STAGE(0, 0);
    STAGE(1, 1);

#pragma unroll
    for (int k = 0; k < STEPS; ++k) {
        const int cur = k % 3;
        // simm16: vmcnt lo[3:0] | expcnt(7)<<4 | lgkmcnt(15)<<8
        if (k == STEPS - 1) __builtin_amdgcn_s_waitcnt(0x0F70);  // vmcnt(0)
        else                __builtin_amdgcn_s_waitcnt(0x0F74);  // vmcnt(4)
        __builtin_amdgcn_s_barrier();
        __asm__ __volatile__("" ::: "memory");   // pin LDS reads below barrier
        if (k + 2 < STEPS) STAGE(k + 2, (k + 2) % 3);

        const unsigned char* As = &Buf[cur][0];
        const unsigned char* Bs = &Buf[cur][8192];
        // ONE b128 per row: [0]=h0 fragment (k 0..31), [1]=h1 (k 32..63)
        i64x2 af[4], bfr[4];
#pragma unroll
        for (int i = 0; i < 4; i++)
            af[i] = *(const i64x2*)&As[(wm * 64 + i * 16 + la) * 64 + rpos];
#pragma unroll
        for (int j = 0; j < 4; j++)
            bfr[j] = *(const i64x2*)&Bs[(wn * 64 + j * 16 + la) * 64 + rpos];
#pragma unroll
        for (int h = 0; h < 2; h++)
#pragma unroll
            for (int i = 0; i < 4; i++)
#pragma unroll
                for (int j = 0; j < 4; j++)
                    acc[i][j] = __builtin_amdgcn_mfma_f32_16x16x32_fp8_fp8(
                        af[i][h], bfr[j][h], acc[i][j], 0, 0, 0);
    }
#undef STAGE

    // epilogue: per-row max over this tile's s-columns, then global atomicMax.
    // C/D layout (verified, dtype-independent): col = lane&15, row = (lane>>4)*4+reg
    const bool diag = (ti == si);
#pragma unroll
    for (int i = 0; i < 4; i++) {
#pragma unroll
        for (int r = 0; r < 4; r++) {
            int tl = wm * 64 + i * 16 + qa * 4 + r;   // local t row
            float m = -2.0f;
#pragma unroll
            for (int j = 0; j < 4; j++) {
                int sl = wn * 64 + j * 16 + la;       // local s col
                float v = acc[i][j][r];
                if (!diag || sl < tl) m = fmaxf(m, v);
            }
#pragma unroll
            for (int off = 1; off < 16; off <<= 1) m = fmaxf(m, __shfl_xor(m, off));
            if (la == 0) atomicMax(&maxsim[b * T_ + t0 + tl], f2ord(m));
        }
    }
}

// ---- Kernel 3: gate + tanh-GELU, one float4 per thread ----
// R15 delta (independent of k_maxsim): fast hardware tanh path.
// tanh(z) = 1 - 2/(1+exp(2z))  =>  gelu(y) = 0.5y(1+tanh) = y*(1 - rcp(1+exp(2z))).
// __expf -> v_exp_f32 (1 transcendental), __builtin_amdgcn_rcpf -> v_rcp_f32.
// Exact limits: y->+inf: exp=inf, rcp=0, gelu=y; y->-inf: exp=0, rcp=1, gelu=0;
// y=0: rcp=0.5, gelu=0. Error ~1e-7 << 0.03 harness tolerance. Replaces
// libm tanhf (~30 inst + large-|x| branches) with ~9 inst.
__device__ __forceinline__ float gelu_tanh(float y) {
    // 2*z = 2*sqrt(2/pi) * (y + 0.044715 y^3)
    float z2 = 1.5957691216057308f * __builtin_fmaf(0.044715f * y, y * y, y);
    float e = __expf(z2);
    float r = __builtin_amdgcn_rcpf(1.0f + e);
    return y * (1.0f - r);
}

__global__ __launch_bounds__(256) void k_gate(const float* __restrict__ x,
                                              const float* __restrict__ log_alpha,
                                              const unsigned* __restrict__ maxsim,
                                              float* __restrict__ out) {
    int idx = blockIdx.x * 256 + threadIdx.x;     // one float4 per thread
    float la = log_alpha[0];
    float alpha = (la > 20.0f) ? la : log1pf(expf(la));
    int row = idx >> 7;                           // 128 float4-threads per row
    float m = fmaxf(ord2f(maxsim[row]), -1.0f);
    float novelty = 1.0f - (m + 1.0f) * 0.5f;
    float gate = 1.0f + alpha * novelty;
    float4 v = ((const float4*)x)[idx];
    float4 o;
    o.x = gelu_tanh(v.x * gate);
    o.y = gelu_tanh(v.y * gate);
    o.z = gelu_tanh(v.z * gate);
    o.w = gelu_tanh(v.w * gate);
    ((float4*)out)[idx] = o;
}

extern "C" void kernel_launch(void* const* d_in, const int* in_sizes, int n_in,
                              void* d_out, int out_size, void* d_ws, size_t ws_size,
                              hipStream_t stream) {
    const float* x = (const float*)d_in[0];
    const float* log_alpha = (const float*)d_in[1];
    float* out = (float*)d_out;

    unsigned* maxsim = (unsigned*)d_ws;
    unsigned char* xn = (unsigned char*)d_ws + 65536;

    const int rows = B_ * T_;                     // 16384
    k_norm<<<rows / 4, 256, 0, stream>>>(x, xn, maxsim);

    dim3 g2(NPAIR, B_);
    k_maxsim<<<g2, 256, 0, stream>>>(xn, maxsim);

    k_gate<<<(B_ * T_ * D_ / 4) / 256, 256, 0, stream>>>(x, log_alpha, maxsim, out);
}